// Round 6
// baseline (220.591 us; speedup 1.0000x reference)
//
#include <hip/hip_runtime.h>
#include <hip/hip_bf16.h>

#define BSZ 131072

typedef __bf16 v8bf __attribute__((ext_vector_type(8)));
typedef __bf16 v4bf __attribute__((ext_vector_type(4)));
typedef float f32x4 __attribute__((ext_vector_type(4)));

constexpr int RPB = 32;        // rows (batch) per block
constexpr int NTHREADS = 512;  // 8 waves
constexpr int LDA  = 264;      // 256 + 8 pad (528B row stride)
constexpr int LDA3 = 72;       // 64 + 8 pad

// d_ws: weights pre-swizzled as MFMA *A-fragments* (m = features).
// A-frag: frag f = ks*MT + mt; lane l elem j = W[mt*16+(l&15)][ks*32+(l>>4)*8+j]
constexpr int OFF_U2  = 0;        // Uw2  [256x256] direct      MT=16
constexpr int OFF_V2  = 65536;    // Vw2  [256x256] direct      MT=16
constexpr int OFF_V2T = 131072;   // Vw2T [256x256] transposed  MT=16
constexpr int OFF_V3  = 196608;   // Vw3  [64x256]  direct      MT=4
constexpr int OFF_V3T = 212992;   // Vw3T [256x64]  transposed  MT=16 (K=64)
constexpr int OFF_L1V = 229376;   // Vw1  [256x32] k<4 else 0   MT=16 (K=32)
constexpr int OFF_L1U = 237568;   // Uw1  [256x32]              MT=16
constexpr int WS_ELEMS = 245760;

__device__ __forceinline__ float tanhf_fast(float x){
  float e = __expf(2.0f * x);
  return 1.0f - 2.0f / (e + 1.0f);
}

__device__ __forceinline__ __bf16 f2bf(float f){
  unsigned u = __builtin_bit_cast(unsigned, f);
  u += 0x8000u;
  unsigned short h = (unsigned short)(u >> 16);
  return __builtin_bit_cast(__bf16, h);
}

// pack two f32 -> bf16 pair (round-half-away), 3 VALU
__device__ __forceinline__ unsigned pack2bf(float lo, float hi){
  unsigned a = __builtin_bit_cast(unsigned, lo) + 0x8000u;
  unsigned b = __builtin_bit_cast(unsigned, hi) + 0x8000u;
  return __builtin_amdgcn_perm(b, a, 0x07060302u);  // D = {b.hi16, a.hi16}
}

// ---- weight pre-swizzle: 8 contiguous ws elems per thread (16B store) ----
__global__ void prep_weights(const float* __restrict__ Vw2,
                             const float* __restrict__ Uw2,
                             const float* __restrict__ Vw3,
                             const float* __restrict__ Vw1,
                             const float* __restrict__ Uw1,
                             __bf16* __restrict__ ws){
  int e8 = blockIdx.x * 256 + threadIdx.x;
  if (e8 >= WS_ELEMS / 8) return;
  int idx8 = e8 * 8;
  int idx, MT, mode; const float* W;
  if      (idx8 <  65536){ idx = idx8;          W = Uw2; mode = 0; MT = 16; }
  else if (idx8 < 131072){ idx = idx8 - 65536;  W = Vw2; mode = 0; MT = 16; }
  else if (idx8 < 196608){ idx = idx8 - 131072; W = Vw2; mode = 1; MT = 16; }
  else if (idx8 < 212992){ idx = idx8 - 196608; W = Vw3; mode = 0; MT = 4;  }
  else if (idx8 < 229376){ idx = idx8 - 212992; W = Vw3; mode = 1; MT = 16; }
  else if (idx8 < 237568){ idx = idx8 - 229376; W = Vw1; mode = 4; MT = 16; }
  else                   { idx = idx8 - 237568; W = Uw1; mode = 4; MT = 16; }
  int l = (idx >> 3) & 63, f = idx >> 9;
  int mt = f % MT, ks = f / MT;
  int m  = mt * 16 + (l & 15);
  int k0 = ks * 32 + ((l >> 4) << 3);
  __bf16 tmp[8];
  #pragma unroll
  for (int j = 0; j < 8; j++){
    int k = k0 + j;
    float v;
    if      (mode == 0) v = W[m * 256 + k];
    else if (mode == 1) v = W[k * 256 + m];
    else                v = (k < 4) ? W[m * 4 + k] : 0.0f;
    tmp[j] = f2bf(v);
  }
  *(uint4*)&ws[idx8] = *(const uint4*)tmp;
}

__global__ __launch_bounds__(NTHREADS, 4) void fused_clf(
    const float* __restrict__ x,
    const float* __restrict__ Vw1,
    const float* __restrict__ Vb1, const float* __restrict__ Vb2,
    const float* __restrict__ Vb3,
    const float* __restrict__ Ub1, const float* __restrict__ Ub2,
    const float* __restrict__ Ub3, const float* __restrict__ Uw3,
    const __bf16* __restrict__ ws,
    float* __restrict__ out)
{
  __shared__ alignas(16) __bf16 b1[RPB][LDA];   // u1 | a1 (a1 persists to the end)
  __shared__ alignas(16) __bf16 b2[RPB][LDA];   // a2 -> t2'
  __shared__ union alignas(16) S3 {
    __bf16 b3[RPB][LDA3];            // a3' = a3*(1-a3^2)
    float  r4[8][RPB][4];            // per-wave fused-reduction partials
  } s3;
  __shared__ float red[RPB][4];
  __shared__ float utile[RPB];

  const int tid  = threadIdx.x;
  const int lane = tid & 63;
  const int wave = tid >> 6;       // 0..7
  const int quad = lane >> 4;
  const int l16  = lane & 15;
  const int row0 = blockIdx.x * RPB;

  // ---- x as B-fragments (batch cols, K=4 zero-padded), built once ----
  v8bf xb[2];
  #pragma unroll
  for (int bt = 0; bt < 2; bt++){
    v8bf z;
    #pragma unroll
    for (int j = 0; j < 8; j++) z[j] = (__bf16)0.0f;
    if (quad == 0){
      float4 xv = ((const float4*)x)[row0 + bt*16 + l16];
      z[0] = f2bf(xv.x); z[1] = f2bf(xv.y); z[2] = f2bf(xv.z); z[3] = f2bf(xv.w);
    }
    xb[bt] = z;
  }

  // ---- layer-1: D[f][b] = W1 @ x^T, single K-step ----
  auto layer1m = [&](const __bf16* __restrict__ Aw, const float* __restrict__ bv,
                     __bf16 (*dst)[LDA]){
    const v8bf* A = (const v8bf*)Aw;
    #pragma unroll
    for (int mi = 0; mi < 2; mi++){
      v8bf af = A[(wave*2 + mi)*64 + lane];
      f32x4 acc[2];
      { f32x4 z = {0.f,0.f,0.f,0.f}; acc[0]=z; acc[1]=z; }
      #pragma unroll
      for (int bt = 0; bt < 2; bt++)
        acc[bt] = __builtin_amdgcn_mfma_f32_16x16x32_bf16(af, xb[bt], acc[bt], 0,0,0);
      int f0 = (wave*2 + mi)*16 + quad*4;
      float4 bv4 = *(const float4*)&bv[f0];
      #pragma unroll
      for (int bt = 0; bt < 2; bt++){
        int b = bt*16 + l16;
        float t0 = tanhf_fast(acc[bt][0] + bv4.x);
        float t1 = tanhf_fast(acc[bt][1] + bv4.y);
        float t2 = tanhf_fast(acc[bt][2] + bv4.z);
        float t3 = tanhf_fast(acc[bt][3] + bv4.w);
        uint2 p = { pack2bf(t0, t1), pack2bf(t2, t3) };
        *(uint2*)&dst[b][f0] = p;
      }
    }
  };

  // ---- core 256x256 GEMM loop: returns acc[mi][bt] ----
  // epi 0: dst = tanh(acc+bias) packed store
  // epi 2: fused u-head: p = sum tanh(acc+bias)*Uw3[f]; partials -> r4
  // epi 3: fused grad_V: v = acc*(1-b1^2); gv = sum v*Vw1[f][:]; partials -> r4
  auto gemmW = [&](const __bf16* __restrict__ Aw, const __bf16 (*act)[LDA],
                   const float* __restrict__ bias, __bf16 (*dst)[LDA], int epi,
                   const float* __restrict__ hw){
    f32x4 acc[2][2];   // [mi][bt]
    #pragma unroll
    for (int mi = 0; mi < 2; mi++){ f32x4 z={0.f,0.f,0.f,0.f}; acc[mi][0]=z; acc[mi][1]=z; }
    const v8bf* A = (const v8bf*)Aw;
    #pragma unroll
    for (int kk = 0; kk < 8; kk++){
      v8bf bf[2];
      #pragma unroll
      for (int bt = 0; bt < 2; bt++)
        bf[bt] = *(const v8bf*)&act[bt*16 + l16][kk*32 + quad*8];
      #pragma unroll
      for (int mi = 0; mi < 2; mi++){
        v8bf af = A[(kk*16 + wave*2 + mi)*64 + lane];
        #pragma unroll
        for (int bt = 0; bt < 2; bt++)
          acc[mi][bt] = __builtin_amdgcn_mfma_f32_16x16x32_bf16(af, bf[bt], acc[mi][bt], 0,0,0);
      }
    }
    if (epi == 0){
      #pragma unroll
      for (int mi = 0; mi < 2; mi++){
        int f0 = (wave*2 + mi)*16 + quad*4;
        float4 bv4 = *(const float4*)&bias[f0];
        #pragma unroll
        for (int bt = 0; bt < 2; bt++){
          int b = bt*16 + l16;
          float t0 = tanhf_fast(acc[mi][bt][0] + bv4.x);
          float t1 = tanhf_fast(acc[mi][bt][1] + bv4.y);
          float t2 = tanhf_fast(acc[mi][bt][2] + bv4.z);
          float t3 = tanhf_fast(acc[mi][bt][3] + bv4.w);
          uint2 p = { pack2bf(t0, t1), pack2bf(t2, t3) };
          *(uint2*)&dst[b][f0] = p;
        }
      }
    } else if (epi == 2){
      float p[2] = {0.f, 0.f};
      #pragma unroll
      for (int mi = 0; mi < 2; mi++){
        int f0 = (wave*2 + mi)*16 + quad*4;
        float4 bv4 = *(const float4*)&bias[f0];
        float4 w4  = *(const float4*)&hw[f0];
        #pragma unroll
        for (int bt = 0; bt < 2; bt++){
          p[bt] += tanhf_fast(acc[mi][bt][0] + bv4.x) * w4.x;
          p[bt] += tanhf_fast(acc[mi][bt][1] + bv4.y) * w4.y;
          p[bt] += tanhf_fast(acc[mi][bt][2] + bv4.z) * w4.z;
          p[bt] += tanhf_fast(acc[mi][bt][3] + bv4.w) * w4.w;
        }
      }
      #pragma unroll
      for (int bt = 0; bt < 2; bt++){
        p[bt] += __shfl_xor(p[bt], 16);
        p[bt] += __shfl_xor(p[bt], 32);
      }
      if (quad == 0){
        s3.r4[wave][l16     ][0] = p[0];
        s3.r4[wave][l16 + 16][0] = p[1];
      }
    } else { // epi == 3
      float gv[2][4];
      #pragma unroll
      for (int bt = 0; bt < 2; bt++)
        #pragma unroll
        for (int j = 0; j < 4; j++) gv[bt][j] = 0.f;
      #pragma unroll
      for (int mi = 0; mi < 2; mi++){
        int f0 = (wave*2 + mi)*16 + quad*4;
        #pragma unroll
        for (int bt = 0; bt < 2; bt++){
          int b = bt*16 + l16;
          v4bf a4 = *(const v4bf*)&dst[b][f0];    // a1
          #pragma unroll
          for (int i = 0; i < 4; i++){
            float a1v = (float)a4[i];
            float v = acc[mi][bt][i] * (1.0f - a1v*a1v);
            float4 w = *(const float4*)&hw[(f0 + i)*4];  // Vw1 row
            gv[bt][0] += v * w.x;
            gv[bt][1] += v * w.y;
            gv[bt][2] += v * w.z;
            gv[bt][3] += v * w.w;
          }
        }
      }
      #pragma unroll
      for (int bt = 0; bt < 2; bt++)
        #pragma unroll
        for (int j = 0; j < 4; j++){
          gv[bt][j] += __shfl_xor(gv[bt][j], 16);
          gv[bt][j] += __shfl_xor(gv[bt][j], 32);
        }
      if (quad == 0){
        #pragma unroll
        for (int bt = 0; bt < 2; bt++){
          f32x4 g = { gv[bt][0], gv[bt][1], gv[bt][2], gv[bt][3] };
          *(f32x4*)&s3.r4[wave][bt*16 + l16][0] = g;
        }
      }
    }
  };

  // ================= phase 1: U layer1 =================
  layer1m(ws + OFF_L1U, Ub1, b1);          // u1 -> b1
  __syncthreads();
  // ================= phase 2: U layer2 + fused u head; V layer1 =================
  gemmW(ws + OFF_U2, b1, Ub2, nullptr, 2, Uw3);   // partials -> r4
  __syncthreads();                          // r4 ready; b1 free
  layer1m(ws + OFF_L1V, Vb1, b1);          // a1 -> b1 (persists to the end)
  if (tid < RPB){                          // finish u
    float z = Ub3[0];
    #pragma unroll
    for (int w = 0; w < 8; w++) z += s3.r4[w][tid][0];
    float u = tanhf_fast(z) * 20.0f;
    utile[tid] = u;
    out[row0 + tid] = u;
  }
  __syncthreads();                          // b1 (a1) ready
  // ================= phase 3: V layer2 =================
  gemmW(ws + OFF_V2, b1, Vb2, b2, 0, nullptr);   // a2 -> b2
  __syncthreads();

  // phase 4: z3 = Vw3 @ a2^T (M=64). wave=(bt,mt). Fused V row-sums + a3' store.
  {
    const int mt = wave & 3, bt = wave >> 2;
    f32x4 acc = {0.f,0.f,0.f,0.f};
    const v8bf* A = (const v8bf*)(ws + OFF_V3);
    #pragma unroll
    for (int kk = 0; kk < 8; kk++){
      v8bf bf = *(const v8bf*)&b2[bt*16 + l16][kk*32 + quad*8];
      v8bf af = A[(kk*4 + mt)*64 + lane];
      acc = __builtin_amdgcn_mfma_f32_16x16x32_bf16(af, bf, acc, 0,0,0);
    }
    int f0 = mt*16 + quad*4;
    int b  = bt*16 + l16;
    float4 bv4 = *(const float4*)&Vb3[f0];
    float t0 = tanhf_fast(acc[0] + bv4.x);
    float t1 = tanhf_fast(acc[1] + bv4.y);
    float t2 = tanhf_fast(acc[2] + bv4.z);
    float t3 = tanhf_fast(acc[3] + bv4.w);
    float sq = t0*t0 + t1*t1 + t2*t2 + t3*t3;
    uint2 p = { pack2bf(t0*(1.0f-t0*t0), t1*(1.0f-t1*t1)),
                pack2bf(t2*(1.0f-t2*t2), t3*(1.0f-t3*t3)) };
    *(uint2*)&s3.b3[b][f0] = p;
    sq += __shfl_xor(sq, 16);
    sq += __shfl_xor(sq, 32);
    if (lane < 16) red[b][mt] = sq;
  }
  __syncthreads();

  // phase 5: t3 = Vw3^T @ a3'^T (K=64); t2' = t3*(1-a2^2) in place. Emit V.
  {
    f32x4 acc[2][2];
    #pragma unroll
    for (int mi = 0; mi < 2; mi++){ f32x4 z={0.f,0.f,0.f,0.f}; acc[mi][0]=z; acc[mi][1]=z; }
    const v8bf* A = (const v8bf*)(ws + OFF_V3T);
    #pragma unroll
    for (int kk = 0; kk < 2; kk++){
      v8bf bf[2];
      #pragma unroll
      for (int bt = 0; bt < 2; bt++)
        bf[bt] = *(const v8bf*)&s3.b3[bt*16 + l16][kk*32 + quad*8];
      #pragma unroll
      for (int mi = 0; mi < 2; mi++){
        v8bf af = A[(kk*16 + wave*2 + mi)*64 + lane];
        #pragma unroll
        for (int bt = 0; bt < 2; bt++)
          acc[mi][bt] = __builtin_amdgcn_mfma_f32_16x16x32_bf16(af, bf[bt], acc[mi][bt], 0,0,0);
      }
    }
    #pragma unroll
    for (int mi = 0; mi < 2; mi++){
      int f0 = (wave*2 + mi)*16 + quad*4;
      #pragma unroll
      for (int bt = 0; bt < 2; bt++){
        int b = bt*16 + l16;
        v4bf a4 = *(const v4bf*)&b2[b][f0];
        float v0 = acc[mi][bt][0] * (1.0f - (float)a4[0]*(float)a4[0]);
        float v1 = acc[mi][bt][1] * (1.0f - (float)a4[1]*(float)a4[1]);
        float v2 = acc[mi][bt][2] * (1.0f - (float)a4[2]*(float)a4[2]);
        float v3 = acc[mi][bt][3] * (1.0f - (float)a4[3]*(float)a4[3]);
        uint2 p = { pack2bf(v0, v1), pack2bf(v2, v3) };
        *(uint2*)&b2[b][f0] = p;
      }
    }
    if (tid < RPB)
      out[BSZ + row0 + tid] = 0.5f * (red[tid][0] + red[tid][1] + red[tid][2] + red[tid][3]);
  }
  __syncthreads();

  // phase 6: s2'-GEMM with fused grad_V head (reads a1 from b1) -> r4
  gemmW(ws + OFF_V2T, b2, nullptr, b1, 3, Vw1);
  __syncthreads();
  if (tid < 4*RPB){
    int b = tid >> 2, j = tid & 3;
    float s = 0.f;
    #pragma unroll
    for (int w = 0; w < 8; w++) s += s3.r4[w][b][j];
    red[b][j] = s;
  }
  __syncthreads();

  // dynamics + Vdot
  if (tid < RPB){
    float4 xv = ((const float4*)x)[row0 + tid];
    float th = xv.y, vv = xv.z, om = xv.w;
    float c = cosf(th), s = sinf(th);
    float dc  = c - 24.7f;
    float dc2 = c*c - 24.7f;
    float f2v = (c*(9.8f*s + 11.5f*vv) + 68.4f*vv - 1.2f*om*om*s) / dc;
    float f3v = (-58.8f*vv*c - 243.5f*vv - s*(208.3f + om*om*c)) / dc2;
    float g2v = (-1.8f*c - 10.9f) / dc;
    float g3v = (9.3f*c + 38.6f) / dc2;
    float Lf = red[tid][0]*vv + red[tid][1]*om + red[tid][2]*f2v + red[tid][3]*f3v;
    float Lg = red[tid][2]*g2v + red[tid][3]*g3v;
    out[2*BSZ + row0 + tid] = Lf + Lg * utile[tid];
  }
}

extern "C" void kernel_launch(void* const* d_in, const int* in_sizes, int n_in,
                              void* d_out, int out_size, void* d_ws, size_t ws_size,
                              hipStream_t stream) {
  const float* x   = (const float*)d_in[0];
  const float* Vw1 = (const float*)d_in[1];
  const float* Vb1 = (const float*)d_in[2];
  const float* Vw2 = (const float*)d_in[3];
  const float* Vb2 = (const float*)d_in[4];
  const float* Vw3 = (const float*)d_in[5];
  const float* Vb3 = (const float*)d_in[6];
  const float* Uw1 = (const float*)d_in[7];
  const float* Ub1 = (const float*)d_in[8];
  const float* Uw2 = (const float*)d_in[9];
  const float* Ub2 = (const float*)d_in[10];
  const float* Uw3 = (const float*)d_in[11];
  const float* Ub3 = (const float*)d_in[12];
  __bf16* ws = (__bf16*)d_ws;
  float* out = (float*)d_out;

  hipLaunchKernelGGL(prep_weights, dim3((WS_ELEMS/8 + 255) / 256), dim3(256), 0, stream,
                     Vw2, Uw2, Vw3, Vw1, Uw1, ws);
  hipLaunchKernelGGL(fused_clf, dim3(BSZ / RPB), dim3(NTHREADS), 0, stream,
                     x, Vw1, Vb1, Vb2, Vb3, Ub1, Ub2, Ub3, Uw3, ws, out);
}

// Round 7
// 204.350 us; speedup vs baseline: 1.0795x; 1.0795x over previous
//
#include <hip/hip_runtime.h>
#include <hip/hip_bf16.h>

#define BSZ 131072

typedef __bf16 v8bf __attribute__((ext_vector_type(8)));
typedef __bf16 v4bf __attribute__((ext_vector_type(4)));
typedef float f32x4 __attribute__((ext_vector_type(4)));

constexpr int RPB = 64;        // rows (batch) per block
constexpr int NTHREADS = 512;  // 8 waves
constexpr int LDA  = 264;      // 256 + 8 pad (528B row stride, 16B aligned)
constexpr int LDA3 = 72;       // 64 + 8 pad

// d_ws: weights pre-swizzled as MFMA *A-fragments* (m = features).
// A-frag: frag f = ks*MT + mt; lane l elem j = W[mt*16+(l&15)][ks*32+(l>>4)*8+j]
constexpr int OFF_U2  = 0;        // Uw2  [256x256] direct      MT=16
constexpr int OFF_V2  = 65536;    // Vw2  [256x256] direct      MT=16
constexpr int OFF_V2T = 131072;   // Vw2T [256x256] transposed  MT=16
constexpr int OFF_V3  = 196608;   // Vw3  [64x256]  direct      MT=4
constexpr int OFF_V3T = 212992;   // Vw3T [256x64]  transposed  MT=16 (K=64)
constexpr int OFF_L1V = 229376;   // Vw1  [256x32] k<4 else 0   MT=16 (K=32)
constexpr int OFF_L1U = 237568;   // Uw1  [256x32]              MT=16
constexpr int WS_ELEMS = 245760;

__device__ __forceinline__ float tanhf_fast(float x){
  float e = __expf(2.0f * x);
  return 1.0f - 2.0f / (e + 1.0f);
}

__device__ __forceinline__ __bf16 f2bf(float f){
  unsigned u = __builtin_bit_cast(unsigned, f);
  u += 0x8000u;
  unsigned short h = (unsigned short)(u >> 16);
  return __builtin_bit_cast(__bf16, h);
}

// pack two f32 -> bf16 pair (round-half-away), 3 VALU
__device__ __forceinline__ unsigned pack2bf(float lo, float hi){
  unsigned a = __builtin_bit_cast(unsigned, lo) + 0x8000u;
  unsigned b = __builtin_bit_cast(unsigned, hi) + 0x8000u;
  return __builtin_amdgcn_perm(b, a, 0x07060302u);  // D = {b.hi16, a.hi16}
}

// ---- weight pre-swizzle: 8 contiguous ws elems per thread (16B store) ----
__global__ void prep_weights(const float* __restrict__ Vw2,
                             const float* __restrict__ Uw2,
                             const float* __restrict__ Vw3,
                             const float* __restrict__ Vw1,
                             const float* __restrict__ Uw1,
                             __bf16* __restrict__ ws){
  int e8 = blockIdx.x * 256 + threadIdx.x;
  if (e8 >= WS_ELEMS / 8) return;
  int idx8 = e8 * 8;
  int idx, MT, mode; const float* W;
  if      (idx8 <  65536){ idx = idx8;          W = Uw2; mode = 0; MT = 16; }
  else if (idx8 < 131072){ idx = idx8 - 65536;  W = Vw2; mode = 0; MT = 16; }
  else if (idx8 < 196608){ idx = idx8 - 131072; W = Vw2; mode = 1; MT = 16; }
  else if (idx8 < 212992){ idx = idx8 - 196608; W = Vw3; mode = 0; MT = 4;  }
  else if (idx8 < 229376){ idx = idx8 - 212992; W = Vw3; mode = 1; MT = 16; }
  else if (idx8 < 237568){ idx = idx8 - 229376; W = Vw1; mode = 4; MT = 16; }
  else                   { idx = idx8 - 237568; W = Uw1; mode = 4; MT = 16; }
  int l = (idx >> 3) & 63, f = idx >> 9;
  int mt = f % MT, ks = f / MT;
  int m  = mt * 16 + (l & 15);
  int k0 = ks * 32 + ((l >> 4) << 3);
  __bf16 tmp[8];
  #pragma unroll
  for (int j = 0; j < 8; j++){
    int k = k0 + j;
    float v;
    if      (mode == 0) v = W[m * 256 + k];
    else if (mode == 1) v = W[k * 256 + m];
    else                v = (k < 4) ? W[m * 4 + k] : 0.0f;
    tmp[j] = f2bf(v);
  }
  *(uint4*)&ws[idx8] = *(const uint4*)tmp;
}

__global__ __launch_bounds__(NTHREADS, 4) void fused_clf(
    const float* __restrict__ x,
    const float* __restrict__ Vw1,
    const float* __restrict__ Vb1, const float* __restrict__ Vb2,
    const float* __restrict__ Vb3,
    const float* __restrict__ Ub1, const float* __restrict__ Ub2,
    const float* __restrict__ Ub3, const float* __restrict__ Uw3,
    const __bf16* __restrict__ ws,
    float* __restrict__ out)
{
  __shared__ alignas(16) __bf16 b1[RPB][LDA];   // u1 -> a2 -> t2' (in place)
  __shared__ alignas(16) __bf16 b2[RPB][LDA];   // a1 (persists to grad_V)
  __shared__ union alignas(16) S3 {
    __bf16 b3[RPB][LDA3];            // a3' = a3*(1-a3^2)
    float  r4[8][RPB][4];            // per-wave fused-reduction partials
  } s3;
  __shared__ float red[RPB][4];
  __shared__ float utile[RPB];

  const int tid  = threadIdx.x;
  const int lane = tid & 63;
  const int wave = tid >> 6;       // 0..7: owns f-tiles {2w, 2w+1}
  const int quad = lane >> 4;
  const int l16  = lane & 15;
  const int row0 = blockIdx.x * RPB;

  // ---- x as B-fragments (batch cols, K=4 zero-padded), built once ----
  v8bf xb[4];
  #pragma unroll
  for (int bt = 0; bt < 4; bt++){
    v8bf z;
    #pragma unroll
    for (int j = 0; j < 8; j++) z[j] = (__bf16)0.0f;
    if (quad == 0){
      float4 xv = ((const float4*)x)[row0 + bt*16 + l16];
      z[0] = f2bf(xv.x); z[1] = f2bf(xv.y); z[2] = f2bf(xv.z); z[3] = f2bf(xv.w);
    }
    xb[bt] = z;
  }

  // ---- layer-1: D[f][b] = W1 @ x^T, single K-step ----
  auto layer1m = [&](const __bf16* __restrict__ Aw, const float* __restrict__ bv,
                     __bf16 (*dst)[LDA]){
    const v8bf* A = (const v8bf*)Aw;
    #pragma unroll
    for (int mi = 0; mi < 2; mi++){
      v8bf af = A[(wave*2 + mi)*64 + lane];
      int f0 = (wave*2 + mi)*16 + quad*4;
      float4 bv4 = *(const float4*)&bv[f0];
      #pragma unroll
      for (int bt = 0; bt < 4; bt++){
        f32x4 acc = {0.f,0.f,0.f,0.f};
        acc = __builtin_amdgcn_mfma_f32_16x16x32_bf16(af, xb[bt], acc, 0,0,0);
        int b = bt*16 + l16;
        float t0 = tanhf_fast(acc[0] + bv4.x);
        float t1 = tanhf_fast(acc[1] + bv4.y);
        float t2 = tanhf_fast(acc[2] + bv4.z);
        float t3 = tanhf_fast(acc[3] + bv4.w);
        uint2 p = { pack2bf(t0, t1), pack2bf(t2, t3) };
        *(uint2*)&dst[b][f0] = p;
      }
    }
  };

  // ---- core 256x256 GEMM: wave = 2 f-tiles x 4 b-tiles (acc[2][4]) ----
  // epi 0: dst = tanh(acc+bias) packed store
  // epi 2: fused u-head: p = sum tanh(acc+bias)*Uw3[f]; partials -> r4
  // epi 3: fused grad_V: v = acc*(1-a1^2) [a1 from dst]; gv = v @ Vw1 -> r4
  auto gemmW = [&](const __bf16* __restrict__ Aw, const __bf16 (*act)[LDA],
                   const float* __restrict__ bias, __bf16 (*dst)[LDA], int epi,
                   const float* __restrict__ hw){
    f32x4 acc[2][4];   // [mi][bt]
    #pragma unroll
    for (int mi = 0; mi < 2; mi++)
      #pragma unroll
      for (int bt = 0; bt < 4; bt++){ f32x4 z={0.f,0.f,0.f,0.f}; acc[mi][bt]=z; }
    const v8bf* A = (const v8bf*)Aw;
    #pragma unroll
    for (int kk = 0; kk < 8; kk++){
      v8bf bf[4];
      #pragma unroll
      for (int bt = 0; bt < 4; bt++)
        bf[bt] = *(const v8bf*)&act[bt*16 + l16][kk*32 + quad*8];
      #pragma unroll
      for (int mi = 0; mi < 2; mi++){
        v8bf af = A[(kk*16 + wave*2 + mi)*64 + lane];
        #pragma unroll
        for (int bt = 0; bt < 4; bt++)
          acc[mi][bt] = __builtin_amdgcn_mfma_f32_16x16x32_bf16(af, bf[bt], acc[mi][bt], 0,0,0);
      }
    }
    if (epi == 0){
      #pragma unroll
      for (int mi = 0; mi < 2; mi++){
        int f0 = (wave*2 + mi)*16 + quad*4;
        float4 bv4 = *(const float4*)&bias[f0];
        #pragma unroll
        for (int bt = 0; bt < 4; bt++){
          int b = bt*16 + l16;
          float t0 = tanhf_fast(acc[mi][bt][0] + bv4.x);
          float t1 = tanhf_fast(acc[mi][bt][1] + bv4.y);
          float t2 = tanhf_fast(acc[mi][bt][2] + bv4.z);
          float t3 = tanhf_fast(acc[mi][bt][3] + bv4.w);
          uint2 p = { pack2bf(t0, t1), pack2bf(t2, t3) };
          *(uint2*)&dst[b][f0] = p;
        }
      }
    } else if (epi == 2){
      float p[4] = {0.f, 0.f, 0.f, 0.f};
      #pragma unroll
      for (int mi = 0; mi < 2; mi++){
        int f0 = (wave*2 + mi)*16 + quad*4;
        float4 bv4 = *(const float4*)&bias[f0];
        float4 w4  = *(const float4*)&hw[f0];
        #pragma unroll
        for (int bt = 0; bt < 4; bt++){
          p[bt] += tanhf_fast(acc[mi][bt][0] + bv4.x) * w4.x;
          p[bt] += tanhf_fast(acc[mi][bt][1] + bv4.y) * w4.y;
          p[bt] += tanhf_fast(acc[mi][bt][2] + bv4.z) * w4.z;
          p[bt] += tanhf_fast(acc[mi][bt][3] + bv4.w) * w4.w;
        }
      }
      #pragma unroll
      for (int bt = 0; bt < 4; bt++){
        p[bt] += __shfl_xor(p[bt], 16);
        p[bt] += __shfl_xor(p[bt], 32);
      }
      if (quad == 0){
        #pragma unroll
        for (int bt = 0; bt < 4; bt++)
          s3.r4[wave][bt*16 + l16][0] = p[bt];
      }
    } else { // epi == 3
      float gv[4][4];
      #pragma unroll
      for (int bt = 0; bt < 4; bt++)
        #pragma unroll
        for (int j = 0; j < 4; j++) gv[bt][j] = 0.f;
      #pragma unroll
      for (int mi = 0; mi < 2; mi++){
        int f0 = (wave*2 + mi)*16 + quad*4;
        #pragma unroll
        for (int i = 0; i < 4; i++){
          float4 w = *(const float4*)&hw[(f0 + i)*4];  // Vw1 row f0+i
          #pragma unroll
          for (int bt = 0; bt < 4; bt++){
            int b = bt*16 + l16;
            float a1v = (float)dst[b][f0 + i];
            float v = acc[mi][bt][i] * (1.0f - a1v*a1v);
            gv[bt][0] += v * w.x;
            gv[bt][1] += v * w.y;
            gv[bt][2] += v * w.z;
            gv[bt][3] += v * w.w;
          }
        }
      }
      #pragma unroll
      for (int bt = 0; bt < 4; bt++)
        #pragma unroll
        for (int j = 0; j < 4; j++){
          gv[bt][j] += __shfl_xor(gv[bt][j], 16);
          gv[bt][j] += __shfl_xor(gv[bt][j], 32);
        }
      if (quad == 0){
        #pragma unroll
        for (int bt = 0; bt < 4; bt++){
          f32x4 g = { gv[bt][0], gv[bt][1], gv[bt][2], gv[bt][3] };
          *(f32x4*)&s3.r4[wave][bt*16 + l16][0] = g;
        }
      }
    }
  };

  // ===== P1: both layer-1s (independent, one barrier) =====
  layer1m(ws + OFF_L1U, Ub1, b1);          // u1 -> b1
  layer1m(ws + OFF_L1V, Vb1, b2);          // a1 -> b2 (persists)
  __syncthreads();
  // ===== P2: U layer2 + fused u head -> r4 =====
  gemmW(ws + OFF_U2, b1, Ub2, nullptr, 2, Uw3);
  __syncthreads();
  // finish u (reads r4) alongside P3
  if (tid < RPB){
    float z = Ub3[0];
    #pragma unroll
    for (int w = 0; w < 8; w++) z += s3.r4[w][tid][0];
    float u = tanhf_fast(z) * 20.0f;
    utile[tid] = u;
    out[row0 + tid] = u;
  }
  // ===== P3: V layer2: a2 = tanh(Vw2@a1+b) -> b1 (u1 dead) =====
  gemmW(ws + OFF_V2, b2, Vb2, b1, 0, nullptr);
  __syncthreads();

  // ===== P4: z3 = Vw3 @ a2^T (M=64). wave=(mt, bt-half); fused V sums =====
  {
    const int mt = wave & 3, bh = wave >> 2;
    const v8bf* A = (const v8bf*)(ws + OFF_V3);
    #pragma unroll
    for (int h = 0; h < 2; h++){
      const int bt = bh + 2*h;
      f32x4 acc = {0.f,0.f,0.f,0.f};
      #pragma unroll
      for (int kk = 0; kk < 8; kk++){
        v8bf bf = *(const v8bf*)&b1[bt*16 + l16][kk*32 + quad*8];
        v8bf af = A[(kk*4 + mt)*64 + lane];
        acc = __builtin_amdgcn_mfma_f32_16x16x32_bf16(af, bf, acc, 0,0,0);
      }
      int f0 = mt*16 + quad*4;
      int b  = bt*16 + l16;
      float4 bv4 = *(const float4*)&Vb3[f0];
      float t0 = tanhf_fast(acc[0] + bv4.x);
      float t1 = tanhf_fast(acc[1] + bv4.y);
      float t2 = tanhf_fast(acc[2] + bv4.z);
      float t3 = tanhf_fast(acc[3] + bv4.w);
      float sq = t0*t0 + t1*t1 + t2*t2 + t3*t3;
      uint2 p = { pack2bf(t0*(1.0f-t0*t0), t1*(1.0f-t1*t1)),
                  pack2bf(t2*(1.0f-t2*t2), t3*(1.0f-t3*t3)) };
      *(uint2*)&s3.b3[b][f0] = p;
      sq += __shfl_xor(sq, 16);
      sq += __shfl_xor(sq, 32);
      if (lane < 16) red[b][mt] = sq;
    }
  }
  __syncthreads();

  // ===== P5: t3 = Vw3^T @ a3'^T (K=64); t2' = t3*(1-a2^2) into b1. Emit V. =====
  {
    f32x4 acc[2][4];
    #pragma unroll
    for (int mi = 0; mi < 2; mi++)
      #pragma unroll
      for (int bt = 0; bt < 4; bt++){ f32x4 z={0.f,0.f,0.f,0.f}; acc[mi][bt]=z; }
    const v8bf* A = (const v8bf*)(ws + OFF_V3T);
    #pragma unroll
    for (int ks = 0; ks < 2; ks++){
      v8bf bf[4];
      #pragma unroll
      for (int bt = 0; bt < 4; bt++)
        bf[bt] = *(const v8bf*)&s3.b3[bt*16 + l16][ks*32 + quad*8];
      #pragma unroll
      for (int mi = 0; mi < 2; mi++){
        v8bf af = A[(ks*16 + wave*2 + mi)*64 + lane];
        #pragma unroll
        for (int bt = 0; bt < 4; bt++)
          acc[mi][bt] = __builtin_amdgcn_mfma_f32_16x16x32_bf16(af, bf[bt], acc[mi][bt], 0,0,0);
      }
    }
    #pragma unroll
    for (int mi = 0; mi < 2; mi++){
      int f0 = (wave*2 + mi)*16 + quad*4;
      #pragma unroll
      for (int bt = 0; bt < 4; bt++){
        int b = bt*16 + l16;
        v4bf a4 = *(const v4bf*)&b1[b][f0];   // a2
        float v0 = acc[mi][bt][0] * (1.0f - (float)a4[0]*(float)a4[0]);
        float v1 = acc[mi][bt][1] * (1.0f - (float)a4[1]*(float)a4[1]);
        float v2 = acc[mi][bt][2] * (1.0f - (float)a4[2]*(float)a4[2]);
        float v3 = acc[mi][bt][3] * (1.0f - (float)a4[3]*(float)a4[3]);
        uint2 p = { pack2bf(v0, v1), pack2bf(v2, v3) };
        *(uint2*)&b1[b][f0] = p;
      }
    }
    if (tid < RPB)
      out[BSZ + row0 + tid] = 0.5f * (red[tid][0] + red[tid][1] + red[tid][2] + red[tid][3]);
  }
  __syncthreads();

  // ===== P6: s2'-GEMM (V2T on t2'=b1) with fused grad_V head (a1 from b2) =====
  gemmW(ws + OFF_V2T, b1, nullptr, b2, 3, Vw1);
  __syncthreads();
  if (tid < 4*RPB){
    int b = tid >> 2, j = tid & 3;
    float s = 0.f;
    #pragma unroll
    for (int w = 0; w < 8; w++) s += s3.r4[w][b][j];
    red[b][j] = s;
  }
  __syncthreads();

  // dynamics + Vdot
  if (tid < RPB){
    float4 xv = ((const float4*)x)[row0 + tid];
    float th = xv.y, vv = xv.z, om = xv.w;
    float c = cosf(th), s = sinf(th);
    float dc  = c - 24.7f;
    float dc2 = c*c - 24.7f;
    float f2v = (c*(9.8f*s + 11.5f*vv) + 68.4f*vv - 1.2f*om*om*s) / dc;
    float f3v = (-58.8f*vv*c - 243.5f*vv - s*(208.3f + om*om*c)) / dc2;
    float g2v = (-1.8f*c - 10.9f) / dc;
    float g3v = (9.3f*c + 38.6f) / dc2;
    float Lf = red[tid][0]*vv + red[tid][1]*om + red[tid][2]*f2v + red[tid][3]*f3v;
    float Lg = red[tid][2]*g2v + red[tid][3]*g3v;
    out[2*BSZ + row0 + tid] = Lf + Lg * utile[tid];
  }
}

extern "C" void kernel_launch(void* const* d_in, const int* in_sizes, int n_in,
                              void* d_out, int out_size, void* d_ws, size_t ws_size,
                              hipStream_t stream) {
  const float* x   = (const float*)d_in[0];
  const float* Vw1 = (const float*)d_in[1];
  const float* Vb1 = (const float*)d_in[2];
  const float* Vw2 = (const float*)d_in[3];
  const float* Vb2 = (const float*)d_in[4];
  const float* Vw3 = (const float*)d_in[5];
  const float* Vb3 = (const float*)d_in[6];
  const float* Uw1 = (const float*)d_in[7];
  const float* Ub1 = (const float*)d_in[8];
  const float* Uw2 = (const float*)d_in[9];
  const float* Ub2 = (const float*)d_in[10];
  const float* Uw3 = (const float*)d_in[11];
  const float* Ub3 = (const float*)d_in[12];
  __bf16* ws = (__bf16*)d_ws;
  float* out = (float*)d_out;

  hipLaunchKernelGGL(prep_weights, dim3((WS_ELEMS/8 + 255) / 256), dim3(256), 0, stream,
                     Vw2, Uw2, Vw3, Vw1, Uw1, ws);
  hipLaunchKernelGGL(fused_clf, dim3(BSZ / RPB), dim3(NTHREADS), 0, stream,
                     x, Vw1, Vb1, Vb2, Vb3, Ub1, Ub2, Ub3, Uw3, ws, out);
}